// Round 1
// baseline (289.480 us; speedup 1.0000x reference)
//
#include <hip/hip_runtime.h>

#define B_   2
#define CIN  128
#define H_   32
#define W_   48
#define HS   32
#define WS2  96
#define LT   3072
#define DI   256
#define NS   16
#define RK   8
#define KK   4
#define NCH  64
#define CHL  48   // NCH*CHL == LT

// canonical token index for scan-order position ls of direction k
__device__ __forceinline__ int lcanon(int k, int ls) {
  if (k == 0) return ls;
  if (k == 1) return (ls & 31) * WS2 + (ls >> 5);
  if (k == 2) return LT - 1 - ls;
  int j = LT - 1 - ls;
  return (j & 31) * WS2 + (j >> 5);
}

// ---------------- kernel 1: token build + in_proj (512x128 per token) -------
__global__ __launch_bounds__(256) void k_inproj(
    const float* __restrict__ rgb, const float* __restrict__ tin,
    const float* __restrict__ wproj, float* __restrict__ xz) {
  __shared__ float xv[CIN][16];   // [c][tok]
  int t  = threadIdx.x;
  int bb = blockIdx.x / 192;
  int lb = blockIdx.x % 192;
  int l0 = lb * 16;
  int h  = l0 / WS2;              // 16-token tiles never cross a row (96%16==0)
  int w20 = l0 % WS2;
  #pragma unroll
  for (int rep = 0; rep < 8; ++rep) {
    int idx = rep * 256 + t;
    int c = idx >> 4, tok = idx & 15;
    int w2 = w20 + tok;
    const float* src = (w2 & 1) ? tin : rgb;
    xv[c][tok] = src[((bb * CIN + c) * HS + h) * W_ + (w2 >> 1)];
  }
  __syncthreads();
  float acc0[16], acc1[16];
  #pragma unroll
  for (int i = 0; i < 16; ++i) { acc0[i] = 0.f; acc1[i] = 0.f; }
  const float* w0p = wproj + t * CIN;
  const float* w1p = wproj + (t + 256) * CIN;
  for (int c = 0; c < CIN; ++c) {
    float w0 = w0p[c], w1 = w1p[c];
    const float4* xr = reinterpret_cast<const float4*>(&xv[c][0]);
    #pragma unroll
    for (int q = 0; q < 4; ++q) {
      float4 x4 = xr[q];
      acc0[4*q+0] += w0 * x4.x; acc1[4*q+0] += w1 * x4.x;
      acc0[4*q+1] += w0 * x4.y; acc1[4*q+1] += w1 * x4.y;
      acc0[4*q+2] += w0 * x4.z; acc1[4*q+2] += w1 * x4.z;
      acc0[4*q+3] += w0 * x4.w; acc1[4*q+3] += w1 * x4.w;
    }
  }
  #pragma unroll
  for (int tok = 0; tok < 16; ++tok) {
    float* dst = xz + ((size_t)bb * LT + (l0 + tok)) * 512;
    dst[t]       = acc0[tok];
    dst[t + 256] = acc1[tok];
  }
}

// ---------------- kernel 2: depthwise 3x3 conv + bias + SiLU ----------------
__global__ __launch_bounds__(256) void k_conv(
    const float* __restrict__ xz, const float* __restrict__ cw,
    const float* __restrict__ cb, float* __restrict__ xc) {
  int t  = threadIdx.x;
  int bb = blockIdx.x / LT;
  int l  = blockIdx.x % LT;
  int h = l / WS2, w2 = l % WS2;
  float wreg[9];
  #pragma unroll
  for (int i = 0; i < 9; ++i) wreg[i] = cw[t * 9 + i];
  float acc = cb[t];
  #pragma unroll
  for (int di = -1; di <= 1; ++di) {
    int hh = h + di;
    if (hh < 0 || hh >= HS) continue;
    #pragma unroll
    for (int dj = -1; dj <= 1; ++dj) {
      int ww = w2 + dj;
      if (ww < 0 || ww >= WS2) continue;
      acc += wreg[(di+1)*3 + (dj+1)] * xz[((size_t)bb * LT + hh * WS2 + ww) * 512 + t];
    }
  }
  float s = acc / (1.f + __expf(-acc));
  xc[((size_t)bb * LT + l) * DI + t] = s;
}

// ---------------- kernel 3: x_proj + dt_proj + softplus ---------------------
__global__ __launch_bounds__(256) void k_deltabc(
    const float* __restrict__ xc, const float* __restrict__ xpw,
    const float* __restrict__ dtw, const float* __restrict__ dtb,
    float* __restrict__ delta, float* __restrict__ Bsb, float* __restrict__ Csb) {
  __shared__ float xv[16][260];
  __shared__ float dts_s[16][RK];
  int t  = threadIdx.x;
  int bi = blockIdx.x;
  int bb = bi / (KK * 192);
  int k  = (bi / 192) % KK;
  int lt = bi % 192;
  for (int i = 0; i < 16; ++i) {
    int ls = lt * 16 + i;
    xv[i][t] = xc[((size_t)bb * LT + lcanon(k, ls)) * DI + t];
  }
  __syncthreads();
  for (int q = t; q < 640; q += 256) {
    int c = q >> 4, i = q & 15;
    const float4* wr4 = reinterpret_cast<const float4*>(xpw + ((size_t)k * 40 + c) * DI);
    const float4* xv4 = reinterpret_cast<const float4*>(&xv[i][0]);
    float acc = 0.f;
    for (int d4 = 0; d4 < 64; ++d4) {
      float4 a = wr4[d4], x = xv4[d4];
      acc += a.x*x.x + a.y*x.y + a.z*x.z + a.w*x.w;
    }
    int ls = lt * 16 + i;
    if (c < RK)          dts_s[i][c] = acc;
    else if (c < RK+NS)  Bsb[(((size_t)bb * KK + k) * LT + ls) * NS + (c - RK)] = acc;
    else                 Csb[(((size_t)bb * KK + k) * LT + ls) * NS + (c - RK - NS)] = acc;
  }
  __syncthreads();
  float w8[RK];
  #pragma unroll
  for (int r = 0; r < RK; ++r) w8[r] = dtw[((size_t)k * DI + t) * RK + r];
  float bias = dtb[k * DI + t];
  for (int i = 0; i < 16; ++i) {
    float acc = bias;
    #pragma unroll
    for (int r = 0; r < RK; ++r) acc += w8[r] * dts_s[i][r];
    float sp = (acc > 20.f) ? acc : log1pf(__expf(acc));
    delta[(((size_t)bb * KK + k) * LT + lt * 16 + i) * DI + t] = sp;
  }
}

// ---------------- kernel 4: scan phase 1 (per-chunk local state) ------------
__global__ __launch_bounds__(256) void k_scan1(
    const float* __restrict__ delta, const float* __restrict__ xc,
    const float* __restrict__ Bsb, const float* __restrict__ Alog,
    float* __restrict__ chH, float* __restrict__ sumd) {
  int t  = threadIdx.x;
  int bi = blockIdx.x;
  int bb = bi / (KK * NCH);
  int k  = (bi / NCH) % KK;
  int ch = bi % NCH;
  size_t bk = (size_t)bb * KK + k;
  float a[NS], h[NS];
  #pragma unroll
  for (int n = 0; n < NS; ++n) {
    a[n] = -__expf(Alog[((size_t)k * DI + t) * NS + n]);
    h[n] = 0.f;
  }
  float sd = 0.f;
  for (int s = 0; s < CHL; ++s) {
    int ls = ch * CHL + s;
    float d = delta[(bk * LT + ls) * DI + t];
    float u = xc[((size_t)bb * LT + lcanon(k, ls)) * DI + t];
    sd += d;
    float du = d * u;
    const float4* Bp = reinterpret_cast<const float4*>(Bsb + (bk * LT + ls) * NS);
    float4 b0 = Bp[0], b1 = Bp[1], b2 = Bp[2], b3 = Bp[3];
    float bv[16] = {b0.x,b0.y,b0.z,b0.w, b1.x,b1.y,b1.z,b1.w,
                    b2.x,b2.y,b2.z,b2.w, b3.x,b3.y,b3.z,b3.w};
    #pragma unroll
    for (int n = 0; n < NS; ++n) h[n] = __expf(d * a[n]) * h[n] + du * bv[n];
  }
  float* outp = chH + ((bk * NCH + ch) * DI + t) * NS;
  #pragma unroll
  for (int n = 0; n < NS; ++n) outp[n] = h[n];
  sumd[(bk * NCH + ch) * DI + t] = sd;
}

// ---------------- kernel 5: scan phase 2 (carry across chunks) --------------
__global__ __launch_bounds__(256) void k_scan2(
    const float* __restrict__ chH, const float* __restrict__ sumd,
    const float* __restrict__ Alog, float* __restrict__ hin) {
  int t  = threadIdx.x;
  int bi = blockIdx.x;
  int bb = bi / (KK * 16);
  int k  = (bi / 16) % KK;
  int dg = bi % 16;
  int d = dg * 16 + (t >> 4);
  int n = t & 15;
  float a = -__expf(Alog[((size_t)k * DI + d) * NS + n]);
  float carry = 0.f;
  size_t bk = (size_t)bb * KK + k;
  for (int ch = 0; ch < NCH; ++ch) {
    size_t base = (bk * NCH + ch) * DI + d;
    hin[base * NS + n] = carry;
    float sd = sumd[base];
    float Hc = chH[base * NS + n];
    carry = __expf(a * sd) * carry + Hc;
  }
}

// ---------------- kernel 6: scan phase 3 (re-scan with carry, emit y) -------
__global__ __launch_bounds__(256) void k_scan3(
    const float* __restrict__ delta, const float* __restrict__ xc,
    const float* __restrict__ Bsb, const float* __restrict__ Csb,
    const float* __restrict__ Alog, const float* __restrict__ Ds,
    const float* __restrict__ hin, float* __restrict__ yall) {
  int t  = threadIdx.x;
  int bi = blockIdx.x;
  int bb = bi / (KK * NCH);
  int k  = (bi / NCH) % KK;
  int ch = bi % NCH;
  size_t bk = (size_t)bb * KK + k;
  float a[NS], h[NS];
  #pragma unroll
  for (int n = 0; n < NS; ++n)
    a[n] = -__expf(Alog[((size_t)k * DI + t) * NS + n]);
  const float4* hp = reinterpret_cast<const float4*>(hin + ((bk * NCH + ch) * DI + t) * NS);
  float4 h0 = hp[0], h1 = hp[1], h2 = hp[2], h3 = hp[3];
  {
    float tmp[16] = {h0.x,h0.y,h0.z,h0.w, h1.x,h1.y,h1.z,h1.w,
                     h2.x,h2.y,h2.z,h2.w, h3.x,h3.y,h3.z,h3.w};
    #pragma unroll
    for (int n = 0; n < NS; ++n) h[n] = tmp[n];
  }
  float dv = Ds[k * DI + t];
  for (int s = 0; s < CHL; ++s) {
    int ls = ch * CHL + s;
    int lc = lcanon(k, ls);
    float d = delta[(bk * LT + ls) * DI + t];
    float u = xc[((size_t)bb * LT + lc) * DI + t];
    float du = d * u;
    const float4* Bp = reinterpret_cast<const float4*>(Bsb + (bk * LT + ls) * NS);
    const float4* Cp = reinterpret_cast<const float4*>(Csb + (bk * LT + ls) * NS);
    float4 b0 = Bp[0], b1 = Bp[1], b2 = Bp[2], b3 = Bp[3];
    float4 c0 = Cp[0], c1 = Cp[1], c2 = Cp[2], c3 = Cp[3];
    float bv[16] = {b0.x,b0.y,b0.z,b0.w, b1.x,b1.y,b1.z,b1.w,
                    b2.x,b2.y,b2.z,b2.w, b3.x,b3.y,b3.z,b3.w};
    float cv[16] = {c0.x,c0.y,c0.z,c0.w, c1.x,c1.y,c1.z,c1.w,
                    c2.x,c2.y,c2.z,c2.w, c3.x,c3.y,c3.z,c3.w};
    float y = 0.f;
    #pragma unroll
    for (int n = 0; n < NS; ++n) {
      h[n] = __expf(d * a[n]) * h[n] + du * bv[n];
      y += h[n] * cv[n];
    }
    y += dv * u;
    yall[(bk * LT + lc) * DI + t] = y;
  }
}

// ---------------- kernel 7: merge + LN + gate + out_proj (odd tokens) -------
__global__ __launch_bounds__(256) void k_out(
    const float* __restrict__ yall, const float* __restrict__ xz,
    const float* __restrict__ g, const float* __restrict__ be,
    const float* __restrict__ opw, float* __restrict__ out) {
  __shared__ float yt[4][DI];
  int t = threadIdx.x;
  int wave = t >> 6, lane = t & 63;
  int gtok = blockIdx.x * 4 + wave;
  int bb = gtok / 1536;
  int m  = gtok % 1536;
  int h = m / W_, w = m % W_;
  int lc = h * WS2 + 2 * w + 1;
  float yv[4];
  #pragma unroll
  for (int j = 0; j < 4; ++j) {
    int d = lane + 64 * j;
    float s = 0.f;
    #pragma unroll
    for (int k = 0; k < KK; ++k)
      s += yall[(((size_t)bb * KK + k) * LT + lc) * DI + d];
    yv[j] = s;
  }
  float sum = yv[0] + yv[1] + yv[2] + yv[3];
  #pragma unroll
  for (int off = 32; off > 0; off >>= 1) sum += __shfl_xor(sum, off, 64);
  float mu = sum * (1.f / DI);
  float sq = 0.f;
  #pragma unroll
  for (int j = 0; j < 4; ++j) { float dd = yv[j] - mu; sq += dd * dd; }
  #pragma unroll
  for (int off = 32; off > 0; off >>= 1) sq += __shfl_xor(sq, off, 64);
  float rs = rsqrtf(sq * (1.f / DI) + 1e-5f);
  #pragma unroll
  for (int j = 0; j < 4; ++j) {
    int d = lane + 64 * j;
    float z = xz[((size_t)bb * LT + lc) * 512 + DI + d];
    float sz = z / (1.f + __expf(-z));
    yt[wave][d] = ((yv[j] - mu) * rs * g[d] + be[d]) * sz;
  }
  __syncthreads();
  const float4* yt4 = reinterpret_cast<const float4*>(&yt[wave][0]);
  int oc0 = lane, oc1 = lane + 64;
  const float4* w0 = reinterpret_cast<const float4*>(opw + (size_t)oc0 * DI);
  const float4* w1 = reinterpret_cast<const float4*>(opw + (size_t)oc1 * DI);
  float acc0 = 0.f, acc1 = 0.f;
  for (int d4 = 0; d4 < 64; ++d4) {
    float4 y4 = yt4[d4];
    float4 a = w0[d4], b = w1[d4];
    acc0 += a.x*y4.x + a.y*y4.y + a.z*y4.z + a.w*y4.w;
    acc1 += b.x*y4.x + b.y*y4.y + b.z*y4.z + b.w*y4.w;
  }
  out[((size_t)(bb * CIN + oc0) * HS + h) * W_ + w] = acc0;
  out[((size_t)(bb * CIN + oc1) * HS + h) * W_ + w] = acc1;
}

extern "C" void kernel_launch(void* const* d_in, const int* in_sizes, int n_in,
                              void* d_out, int out_size, void* d_ws, size_t ws_size,
                              hipStream_t stream) {
  const float* rgb  = (const float*)d_in[0];
  const float* tin  = (const float*)d_in[1];
  const float* ipw  = (const float*)d_in[2];
  const float* cw   = (const float*)d_in[3];
  const float* cb   = (const float*)d_in[4];
  const float* xpw  = (const float*)d_in[5];
  const float* dtw  = (const float*)d_in[6];
  const float* dtb  = (const float*)d_in[7];
  const float* Alog = (const float*)d_in[8];
  const float* Ds   = (const float*)d_in[9];
  const float* g    = (const float*)d_in[10];
  const float* be   = (const float*)d_in[11];
  const float* opw  = (const float*)d_in[12];
  float* out = (float*)d_out;

  float* ws    = (float*)d_ws;
  float* xz    = ws;                  // B*L*512          = 3,145,728
  float* xc    = xz    + 3145728;     // B*L*256          = 1,572,864
  float* delta = xc    + 1572864;     // B*K*L*256        = 6,291,456
  float* Bsb   = delta + 6291456;     // B*K*L*16         =   393,216
  float* Csb   = Bsb   + 393216;      //                  =   393,216
  float* chH   = Csb   + 393216;      // B*K*NCH*256*16   = 2,097,152
  float* sumd  = chH   + 2097152;     // B*K*NCH*256      =   131,072
  float* hin   = sumd  + 131072;      //                  = 2,097,152
  float* yall  = hin   + 2097152;     // B*K*L*256        = 6,291,456

  k_inproj <<<384,  256, 0, stream>>>(rgb, tin, ipw, xz);
  k_conv   <<<6144, 256, 0, stream>>>(xz, cw, cb, xc);
  k_deltabc<<<1536, 256, 0, stream>>>(xc, xpw, dtw, dtb, delta, Bsb, Csb);
  k_scan1  <<<512,  256, 0, stream>>>(delta, xc, Bsb, Alog, chH, sumd);
  k_scan2  <<<128,  256, 0, stream>>>(chH, sumd, Alog, hin);
  k_scan3  <<<512,  256, 0, stream>>>(delta, xc, Bsb, Csb, Alog, Ds, hin, yall);
  k_out    <<<768,  256, 0, stream>>>(yall, xz, g, be, opw, out);
}

// Round 2
// 200.385 us; speedup vs baseline: 1.4446x; 1.4446x over previous
//
#include <hip/hip_runtime.h>

#define B_   2
#define CIN  128
#define H_   32
#define W_   48
#define HS   32
#define WS2  96
#define LT   3072
#define DI   256
#define NS   16
#define RK   8
#define KK   4
#define NCH  64
#define CHL  48   // NCH*CHL == LT

// canonical token index for scan-order position ls of direction k
__device__ __forceinline__ int lcanon(int k, int ls) {
  if (k == 0) return ls;
  if (k == 1) return (ls & 31) * WS2 + (ls >> 5);
  if (k == 2) return LT - 1 - ls;
  int j = LT - 1 - ls;
  return (j & 31) * WS2 + (j >> 5);
}

// ---------------- kernel 1: token build + in_proj (512x128 per token) -------
__global__ __launch_bounds__(256) void k_inproj(
    const float* __restrict__ rgb, const float* __restrict__ tin,
    const float* __restrict__ wproj, float* __restrict__ xz) {
  __shared__ float xv[CIN][16];   // [c][tok]
  int t  = threadIdx.x;
  int bb = blockIdx.x / 192;
  int lb = blockIdx.x % 192;
  int l0 = lb * 16;
  int h  = l0 / WS2;              // 16-token tiles never cross a row (96%16==0)
  int w20 = l0 % WS2;
  #pragma unroll
  for (int rep = 0; rep < 8; ++rep) {
    int idx = rep * 256 + t;
    int c = idx >> 4, tok = idx & 15;
    int w2 = w20 + tok;
    const float* src = (w2 & 1) ? tin : rgb;
    xv[c][tok] = src[((bb * CIN + c) * HS + h) * W_ + (w2 >> 1)];
  }
  __syncthreads();
  float acc0[16], acc1[16];
  #pragma unroll
  for (int i = 0; i < 16; ++i) { acc0[i] = 0.f; acc1[i] = 0.f; }
  const float* w0p = wproj + t * CIN;
  const float* w1p = wproj + (t + 256) * CIN;
  for (int c = 0; c < CIN; ++c) {
    float w0 = w0p[c], w1 = w1p[c];
    const float4* xr = reinterpret_cast<const float4*>(&xv[c][0]);
    #pragma unroll
    for (int q = 0; q < 4; ++q) {
      float4 x4 = xr[q];
      acc0[4*q+0] += w0 * x4.x; acc1[4*q+0] += w1 * x4.x;
      acc0[4*q+1] += w0 * x4.y; acc1[4*q+1] += w1 * x4.y;
      acc0[4*q+2] += w0 * x4.z; acc1[4*q+2] += w1 * x4.z;
      acc0[4*q+3] += w0 * x4.w; acc1[4*q+3] += w1 * x4.w;
    }
  }
  #pragma unroll
  for (int tok = 0; tok < 16; ++tok) {
    float* dst = xz + ((size_t)bb * LT + (l0 + tok)) * 512;
    dst[t]       = acc0[tok];
    dst[t + 256] = acc1[tok];
  }
}

// ---------------- kernel 2: depthwise 3x3 conv + bias + SiLU (sliding) ------
__global__ __launch_bounds__(256) void k_conv(
    const float* __restrict__ xz, const float* __restrict__ cw,
    const float* __restrict__ cbias, float* __restrict__ xc) {
  int t  = threadIdx.x;
  int bi = blockIdx.x;           // 2b * 32h * 4q
  int bb = bi >> 7;
  int h  = (bi >> 2) & 31;
  int q  = bi & 3;
  int w0 = q * 24;
  float wreg[9];
  #pragma unroll
  for (int i = 0; i < 9; ++i) wreg[i] = cw[t * 9 + i];
  float bias = cbias[t];
  bool hm = (h > 0), hp = (h < HS - 1);
  const size_t rowb = ((size_t)bb * LT + h * WS2) * 512 + t;   // col c at rowb + c*512
  const size_t up = (size_t)WS2 * 512;
  float a0=0,a1=0,b0=0,b1=0,c0=0,c1=0;  // rows a=h-1,b=h,c=h+1; cols 0=prev,1=cur
  if (w0 > 0) {
    size_t o = rowb + (size_t)(w0 - 1) * 512;
    b0 = xz[o];
    if (hm) a0 = xz[o - up];
    if (hp) c0 = xz[o + up];
  }
  {
    size_t o = rowb + (size_t)w0 * 512;
    b1 = xz[o];
    if (hm) a1 = xz[o - up];
    if (hp) c1 = xz[o + up];
  }
  #pragma unroll 4
  for (int s = 0; s < 24; ++s) {
    int w2 = w0 + s;
    float a2 = 0, b2 = 0, c2 = 0;
    if (w2 + 1 < WS2) {
      size_t o = rowb + (size_t)(w2 + 1) * 512;
      b2 = xz[o];
      if (hm) a2 = xz[o - up];
      if (hp) c2 = xz[o + up];
    }
    float acc = bias
      + wreg[0]*a0 + wreg[1]*a1 + wreg[2]*a2
      + wreg[3]*b0 + wreg[4]*b1 + wreg[5]*b2
      + wreg[6]*c0 + wreg[7]*c1 + wreg[8]*c2;
    float sv = acc / (1.f + __expf(-acc));
    xc[((size_t)bb * LT + h * WS2 + w2) * DI + t] = sv;
    a0=a1; a1=a2; b0=b1; b1=b2; c0=c1; c1=c2;
  }
}

// -------- kernel 3: x_proj(all 4 dirs) + dt_proj + softplus, one xc pass ----
__global__ __launch_bounds__(256) void k_deltabc(
    const float* __restrict__ xc, const float* __restrict__ xpw,
    const float* __restrict__ dtw, const float* __restrict__ dtb,
    float* __restrict__ delta, float* __restrict__ Bsb, float* __restrict__ Csb) {
  __shared__ float xv[16][260];        // [tok][d]
  __shared__ float outs2[128][17];     // B/C staging: row = k*32 + (c40-8)
  __shared__ float dts_s[KK][16][RK];  // dt low-rank per (k, tok)
  int t  = threadIdx.x;
  int bb = blockIdx.x / 192;
  int lt = blockIdx.x % 192;
  for (int i = 0; i < 16; ++i)
    xv[i][t] = xc[((size_t)bb * LT + lt * 16 + i) * DI + t];
  __syncthreads();

  int i  = t & 15;        // token
  int cb = t >> 4;        // channel base [0,16)
  float acc[10];
  #pragma unroll
  for (int j = 0; j < 10; ++j) acc[j] = 0.f;
  const float4* wp[10];
  #pragma unroll
  for (int j = 0; j < 10; ++j)
    wp[j] = reinterpret_cast<const float4*>(xpw + (size_t)(cb + 16 * j) * DI);
  const float4* xr = reinterpret_cast<const float4*>(&xv[i][0]);
  for (int d4 = 0; d4 < 64; ++d4) {
    float4 x4 = xr[d4];
    #pragma unroll
    for (int j = 0; j < 10; ++j) {
      float4 w = wp[j][d4];
      acc[j] += w.x*x4.x + w.y*x4.y + w.z*x4.z + w.w*x4.w;
    }
  }
  #pragma unroll
  for (int j = 0; j < 10; ++j) {
    int cc  = cb + 16 * j;
    int k   = (cc * 205) >> 13;        // cc / 40 for cc < 160
    int c40 = cc - 40 * k;
    if (c40 < RK) dts_s[k][i][c40] = acc[j];
    else          outs2[k * 32 + (c40 - RK)][i] = acc[j];
  }
  __syncthreads();

  // coalesced B/C writeout (64B rows)
  {
    int n = t & 15, tok = t >> 4;
    int lc = lt * 16 + tok;
    int lw = (lc % WS2) * 32 + lc / WS2;
    int lsA[4] = {lc, lw, LT - 1 - lc, LT - 1 - lw};
    #pragma unroll
    for (int k = 0; k < KK; ++k) {
      size_t row = ((size_t)(bb * KK + k) * LT + lsA[k]) * NS + n;
      Bsb[row] = outs2[k * 32 + n][tok];
      Csb[row] = outs2[k * 32 + 16 + n][tok];
    }
  }

  // dt_proj + softplus + delta write (coalesced over d = t)
  float4 wA[KK][2]; float biasA[KK];
  #pragma unroll
  for (int k = 0; k < KK; ++k) {
    const float* wr = dtw + ((size_t)k * DI + t) * RK;
    wA[k][0] = *reinterpret_cast<const float4*>(wr);
    wA[k][1] = *reinterpret_cast<const float4*>(wr + 4);
    biasA[k] = dtb[k * DI + t];
  }
  for (int i2 = 0; i2 < 16; ++i2) {
    int lc = lt * 16 + i2;
    int lw = (lc % WS2) * 32 + lc / WS2;
    int lsB[4] = {lc, lw, LT - 1 - lc, LT - 1 - lw};
    #pragma unroll
    for (int k = 0; k < KK; ++k) {
      const float* dp = &dts_s[k][i2][0];
      float4 r0 = *reinterpret_cast<const float4*>(dp);
      float4 r1 = *reinterpret_cast<const float4*>(dp + 4);
      float x = biasA[k]
        + wA[k][0].x*r0.x + wA[k][0].y*r0.y + wA[k][0].z*r0.z + wA[k][0].w*r0.w
        + wA[k][1].x*r1.x + wA[k][1].y*r1.y + wA[k][1].z*r1.z + wA[k][1].w*r1.w;
      float sp = fmaxf(x, 0.f) + __logf(1.f + __expf(-fabsf(x)));
      delta[(((size_t)bb * KK + k) * LT + lsB[k]) * DI + t] = sp;
    }
  }
}

// ---------------- kernel 4: scan phase 1 (per-chunk local state) ------------
__global__ __launch_bounds__(256) void k_scan1(
    const float* __restrict__ delta, const float* __restrict__ xc,
    const float* __restrict__ Bsb, const float* __restrict__ Alog,
    float* __restrict__ chH, float* __restrict__ sumd) {
  int t  = threadIdx.x;
  int bi = blockIdx.x;
  int bb = bi / (KK * NCH);
  int k  = (bi / NCH) % KK;
  int ch = bi % NCH;
  size_t bk = (size_t)bb * KK + k;
  float a[NS], h[NS];
  #pragma unroll
  for (int n = 0; n < NS; ++n) {
    a[n] = -__expf(Alog[((size_t)k * DI + t) * NS + n]);
    h[n] = 0.f;
  }
  float sd = 0.f;
  for (int s = 0; s < CHL; ++s) {
    int ls = ch * CHL + s;
    float d = delta[(bk * LT + ls) * DI + t];
    float u = xc[((size_t)bb * LT + lcanon(k, ls)) * DI + t];
    sd += d;
    float du = d * u;
    const float4* Bp = reinterpret_cast<const float4*>(Bsb + (bk * LT + ls) * NS);
    float4 b0 = Bp[0], b1 = Bp[1], b2 = Bp[2], b3 = Bp[3];
    float bv[16] = {b0.x,b0.y,b0.z,b0.w, b1.x,b1.y,b1.z,b1.w,
                    b2.x,b2.y,b2.z,b2.w, b3.x,b3.y,b3.z,b3.w};
    #pragma unroll
    for (int n = 0; n < NS; ++n) h[n] = __expf(d * a[n]) * h[n] + du * bv[n];
  }
  float* outp = chH + ((bk * NCH + ch) * DI + t) * NS;
  #pragma unroll
  for (int n = 0; n < NS; ++n) outp[n] = h[n];
  sumd[(bk * NCH + ch) * DI + t] = sd;
}

// ---------------- kernel 5: scan phase 2 (carry across chunks) --------------
__global__ __launch_bounds__(256) void k_scan2(
    const float* __restrict__ chH, const float* __restrict__ sumd,
    const float* __restrict__ Alog, float* __restrict__ hin) {
  int t  = threadIdx.x;
  int bi = blockIdx.x;
  int bb = bi / (KK * 16);
  int k  = (bi / 16) % KK;
  int dg = bi % 16;
  int d = dg * 16 + (t >> 4);
  int n = t & 15;
  float a = -__expf(Alog[((size_t)k * DI + d) * NS + n]);
  float carry = 0.f;
  size_t bk = (size_t)bb * KK + k;
  for (int ch = 0; ch < NCH; ++ch) {
    size_t base = (bk * NCH + ch) * DI + d;
    hin[base * NS + n] = carry;
    float sd = sumd[base];
    float Hc = chH[base * NS + n];
    carry = __expf(a * sd) * carry + Hc;
  }
}

// ------- kernel 6: scan phase 3 (re-scan with carry, emit y odd-only) -------
__global__ __launch_bounds__(256) void k_scan3(
    const float* __restrict__ delta, const float* __restrict__ xc,
    const float* __restrict__ Bsb, const float* __restrict__ Csb,
    const float* __restrict__ Alog, const float* __restrict__ Ds,
    const float* __restrict__ hin, float* __restrict__ yhalf) {
  int t  = threadIdx.x;
  int bi = blockIdx.x;
  int bb = bi / (KK * NCH);
  int k  = (bi / NCH) % KK;
  int ch = bi % NCH;
  size_t bk = (size_t)bb * KK + k;
  float a[NS], h[NS];
  #pragma unroll
  for (int n = 0; n < NS; ++n)
    a[n] = -__expf(Alog[((size_t)k * DI + t) * NS + n]);
  const float4* hp = reinterpret_cast<const float4*>(hin + ((bk * NCH + ch) * DI + t) * NS);
  float4 h0 = hp[0], h1 = hp[1], h2 = hp[2], h3 = hp[3];
  {
    float tmp[16] = {h0.x,h0.y,h0.z,h0.w, h1.x,h1.y,h1.z,h1.w,
                     h2.x,h2.y,h2.z,h2.w, h3.x,h3.y,h3.z,h3.w};
    #pragma unroll
    for (int n = 0; n < NS; ++n) h[n] = tmp[n];
  }
  float dv = Ds[k * DI + t];
  for (int s = 0; s < CHL; ++s) {
    int ls = ch * CHL + s;
    int lc = lcanon(k, ls);
    float d = delta[(bk * LT + ls) * DI + t];
    float u = xc[((size_t)bb * LT + lc) * DI + t];
    float du = d * u;
    const float4* Bp = reinterpret_cast<const float4*>(Bsb + (bk * LT + ls) * NS);
    const float4* Cp = reinterpret_cast<const float4*>(Csb + (bk * LT + ls) * NS);
    float4 b0 = Bp[0], b1 = Bp[1], b2 = Bp[2], b3 = Bp[3];
    float4 c0 = Cp[0], c1 = Cp[1], c2 = Cp[2], c3 = Cp[3];
    float bv[16] = {b0.x,b0.y,b0.z,b0.w, b1.x,b1.y,b1.z,b1.w,
                    b2.x,b2.y,b2.z,b2.w, b3.x,b3.y,b3.z,b3.w};
    float cv[16] = {c0.x,c0.y,c0.z,c0.w, c1.x,c1.y,c1.z,c1.w,
                    c2.x,c2.y,c2.z,c2.w, c3.x,c3.y,c3.z,c3.w};
    float y = 0.f;
    #pragma unroll
    for (int n = 0; n < NS; ++n) {
      h[n] = __expf(d * a[n]) * h[n] + du * bv[n];
      y += h[n] * cv[n];
    }
    y += dv * u;
    if (lc & 1)
      yhalf[(bk * (LT/2) + (lc >> 1)) * DI + t] = y;
  }
}

// ---------------- kernel 7: merge + LN + gate + out_proj (8 tok/block) ------
__global__ __launch_bounds__(256) void k_out(
    const float* __restrict__ yhalf, const float* __restrict__ xz,
    const float* __restrict__ g, const float* __restrict__ be,
    const float* __restrict__ opw, float* __restrict__ out) {
  __shared__ float yt[8][264];
  int t = threadIdx.x;
  int bb   = blockIdx.x / 192;
  int tile = blockIdx.x % 192;
  {
    int lane = t & 31, tok = t >> 5;       // 8 tokens, 32 lanes each
    int m = tile * 8 + tok;                // odd-token index within batch
    int lc = (m / W_) * WS2 + (m % W_) * 2 + 1;
    float yv[8];
    #pragma unroll
    for (int j = 0; j < 8; ++j) {
      int d = lane + 32 * j;
      float s = 0.f;
      #pragma unroll
      for (int k = 0; k < KK; ++k)
        s += yhalf[(((size_t)bb * KK + k) * (LT/2) + m) * DI + d];
      yv[j] = s;
    }
    float sum = 0.f;
    #pragma unroll
    for (int j = 0; j < 8; ++j) sum += yv[j];
    #pragma unroll
    for (int off = 16; off > 0; off >>= 1) sum += __shfl_xor(sum, off, 64);
    float mu = sum * (1.f / DI);
    float sq = 0.f;
    #pragma unroll
    for (int j = 0; j < 8; ++j) { float dd = yv[j] - mu; sq += dd * dd; }
    #pragma unroll
    for (int off = 16; off > 0; off >>= 1) sq += __shfl_xor(sq, off, 64);
    float rs = rsqrtf(sq * (1.f / DI) + 1e-5f);
    #pragma unroll
    for (int j = 0; j < 8; ++j) {
      int d = lane + 32 * j;
      float z = xz[((size_t)bb * LT + lc) * 512 + DI + d];
      float sz = z / (1.f + __expf(-z));
      yt[tok][d] = ((yv[j] - mu) * rs * g[d] + be[d]) * sz;
    }
  }
  __syncthreads();
  int i = t & 7, og = t >> 3;              // token, oc-group [0,32)
  const float4* yr = reinterpret_cast<const float4*>(&yt[i][0]);
  float acc[4] = {0.f, 0.f, 0.f, 0.f};
  const float4* wp[4];
  #pragma unroll
  for (int j = 0; j < 4; ++j)
    wp[j] = reinterpret_cast<const float4*>(opw + (size_t)(og + 32 * j) * DI);
  for (int d4 = 0; d4 < 64; ++d4) {
    float4 y4 = yr[d4];
    #pragma unroll
    for (int j = 0; j < 4; ++j) {
      float4 w = wp[j][d4];
      acc[j] += w.x*y4.x + w.y*y4.y + w.z*y4.z + w.w*y4.w;
    }
  }
  int m = tile * 8 + i;
  int h = m / W_, w = m % W_;
  #pragma unroll
  for (int j = 0; j < 4; ++j) {
    int oc = og + 32 * j;
    out[((size_t)(bb * CIN + oc) * HS + h) * W_ + w] = acc[j];
  }
}

extern "C" void kernel_launch(void* const* d_in, const int* in_sizes, int n_in,
                              void* d_out, int out_size, void* d_ws, size_t ws_size,
                              hipStream_t stream) {
  const float* rgb  = (const float*)d_in[0];
  const float* tin  = (const float*)d_in[1];
  const float* ipw  = (const float*)d_in[2];
  const float* cw   = (const float*)d_in[3];
  const float* cb   = (const float*)d_in[4];
  const float* xpw  = (const float*)d_in[5];
  const float* dtw  = (const float*)d_in[6];
  const float* dtb  = (const float*)d_in[7];
  const float* Alog = (const float*)d_in[8];
  const float* Ds   = (const float*)d_in[9];
  const float* g    = (const float*)d_in[10];
  const float* be   = (const float*)d_in[11];
  const float* opw  = (const float*)d_in[12];
  float* out = (float*)d_out;

  float* ws    = (float*)d_ws;
  float* xz    = ws;                  // B*L*512          = 3,145,728
  float* xc    = xz    + 3145728;     // B*L*256          = 1,572,864
  float* delta = xc    + 1572864;     // B*K*L*256        = 6,291,456
  float* Bsb   = delta + 6291456;     // B*K*L*16         =   393,216
  float* Csb   = Bsb   + 393216;      //                  =   393,216
  float* chH   = Csb   + 393216;      // B*K*NCH*256*16   = 2,097,152
  float* sumd  = chH   + 2097152;     // B*K*NCH*256      =   131,072
  float* hin   = sumd  + 131072;      //                  = 2,097,152
  float* yhalf = hin   + 2097152;     // B*K*(L/2)*256    = 3,145,728

  k_inproj <<<384, 256, 0, stream>>>(rgb, tin, ipw, xz);
  k_conv   <<<256, 256, 0, stream>>>(xz, cw, cb, xc);
  k_deltabc<<<384, 256, 0, stream>>>(xc, xpw, dtw, dtb, delta, Bsb, Csb);
  k_scan1  <<<512, 256, 0, stream>>>(delta, xc, Bsb, Alog, chH, sumd);
  k_scan2  <<<128, 256, 0, stream>>>(chH, sumd, Alog, hin);
  k_scan3  <<<512, 256, 0, stream>>>(delta, xc, Bsb, Csb, Alog, Ds, hin, yhalf);
  k_out    <<<384, 256, 0, stream>>>(yhalf, xz, g, be, opw, out);
}